// Round 12
// baseline (168.713 us; speedup 1.0000x reference)
//
#include <hip/hip_runtime.h>
#include <hip/hip_bf16.h>

#define BB 8
#define NN 2048
#define FF 128

typedef short bh8 __attribute__((ext_vector_type(8)));
typedef float fl4 __attribute__((ext_vector_type(4)));
typedef unsigned short u16;
typedef union { bh8 v; unsigned u[4]; } bh8u;

__device__ __forceinline__ u16 f2bf(float x) {
    unsigned u = __float_as_uint(x);
    return (u16)((u + 0x7FFFu + ((u >> 16) & 1u)) >> 16);
}

// ---------------------------------------------------------------------------
// kernel 1: h = feat @ W + b -> htg bf16 transposed [b][o][n]; esrc, edst.
// (R6 version — best measured.)
// ---------------------------------------------------------------------------
__global__ __launch_bounds__(256) void k_h(
    const float* __restrict__ feat, const float* __restrict__ W,
    const float* __restrict__ bias, const float* __restrict__ a,
    u16* __restrict__ htg, float* __restrict__ esrc, float* __restrict__ edst)
{
    __shared__ float fsh[8][FF];
    __shared__ float red[2][2][8];
    const int t = threadIdx.x;
    const long row0 = (long)blockIdx.x * 8;

    ((float4*)&fsh[0][0])[t] = ((const float4*)(feat + row0 * FF))[t];
    __syncthreads();

    const int o = t & 127;
    const int half = t >> 7;
    float acc[4] = {0.f, 0.f, 0.f, 0.f};
    #pragma unroll 4
    for (int k = 0; k < FF; ++k) {
        const float w = W[k * FF + o];
        #pragma unroll
        for (int r = 0; r < 4; ++r)
            acc[r] = fmaf(fsh[half * 4 + r][k], w, acc[r]);
    }
    const float bo = bias[o];
    const float as = a[o];
    const float ad = a[FF + o];
    float ps[4], pd[4];
    #pragma unroll
    for (int r = 0; r < 4; ++r) {
        acc[r] += bo;
        ps[r] = acc[r] * as;
        pd[r] = acc[r] * ad;
    }
    {
        const int bI = (int)(row0 >> 11);
        const int nloc = (int)(row0 & 2047) + half * 4;
        ushort4 hv;
        hv.x = f2bf(acc[0]); hv.y = f2bf(acc[1]);
        hv.z = f2bf(acc[2]); hv.w = f2bf(acc[3]);
        *(ushort4*)&htg[((long)bI * FF + o) * NN + nloc] = hv;
    }
    #pragma unroll
    for (int r = 0; r < 4; ++r) {
        #pragma unroll
        for (int off = 32; off > 0; off >>= 1) {
            ps[r] += __shfl_down(ps[r], off, 64);
            pd[r] += __shfl_down(pd[r], off, 64);
        }
    }
    const int wv = (t >> 6) & 1;
    if ((t & 63) == 0) {
        #pragma unroll
        for (int r = 0; r < 4; ++r) {
            red[half][wv][r]     = ps[r];
            red[half][wv][4 + r] = pd[r];
        }
    }
    __syncthreads();
    if (t < 16) {
        const int hh = t >> 3, idx = t & 7;
        const float v = red[hh][0][idx] + red[hh][1][idx];
        const long row = row0 + hh * 4 + (idx & 3);
        if (idx < 4) esrc[row] = v;
        else         edst[row] = v;
    }
}

// ---------------------------------------------------------------------------
// kernel 2 (fused attn, no k_pack): RB=16, grid 1024, 4 waves m-split within
// each 128-m window (wave w owns m-chunk w*32..w*32+31). H window (128x128
// bf16, 32 KB) staged global->reg->LDS with swizzled ds_write
// (LDS[o][c] = global[o][c ^ (o&7)]) -> bank-balanced b128 on both sides.
// adj read DIRECTLY (2 int4/lane/window, prefetched one window ahead) — the
// one mandatory 134 MB HBM stream rides this kernel. Single Hs buffer
// overlaid on epilogue accbuf; 2 barriers/window; T14 split: loads at window
// top, ds_write after barrier 2. psum via ones-MFMA.
// ---------------------------------------------------------------------------
__global__ __launch_bounds__(256, 3) void k_attn(
    const int* __restrict__ adj, const float* __restrict__ mask,
    const u16* __restrict__ htg, const float* __restrict__ esrc,
    const float* __restrict__ edst, float* __restrict__ out)
{
    __shared__ float accbuf[4][16][FF + 4];   // 33.8 KB (Hs overlay)
    __shared__ float psum_sh[4][16];
    u16* Hs = (u16*)&accbuf[0][0][0];         // [o 0..127][m 0..127], row 128 u16

    const int t = threadIdx.x;
    const int b = blockIdx.x & 7;               // batch -> XCD affinity
    const int n0 = (blockIdx.x >> 3) * 16;      // 128 row-tiles per batch
    const int w = t >> 6, lane = t & 63;
    const int lr = lane & 15, g = lane >> 4;

    // per-wave gmax over edst[b][:] (8 KB, L2-hot)
    float gmx = -3.4e38f;
    {
        const float4* edp4 = (const float4*)(edst + b * NN);
        #pragma unroll
        for (int i = 0; i < 8; ++i) {
            const float4 v = edp4[lane + 64 * i];
            gmx = fmaxf(gmx, fmaxf(fmaxf(v.x, v.y), fmaxf(v.z, v.w)));
        }
        #pragma unroll
        for (int off = 32; off > 0; off >>= 1)
            gmx = fmaxf(gmx, __shfl_xor(gmx, off, 64));
    }

    const float es = esrc[b * NN + n0 + lr];     // this lane's P-row constant
    const float mt0 = es + gmx;
    const float M = fmaxf(mt0, 0.01f * mt0);     // leaky(es+gmax) >= rowmax

    const u16*   hB  = htg + (long)b * FF * NN;
    const float* edb = edst + b * NN;
    const int*   ajb = adj + ((long)b * NN + n0 + lr) * NN;   // this lane's adj row
    const int mw = w * 32 + g * 8;               // lane's m-offset within window

    // staging geometry: thread t = (so = t>>4, c = t&15); source LINEAR chunk c
    // of row so+16i (coalesced float4); dest LDS[o][c ^ (o&7)] (swizzled write).
    const int so = t >> 4;
    const int sc = t & 15;
    const u16* sgl = hB + (long)so * NN + sc * 8;              // + i*16*NN + win*128
    const int sldst = so * 128 + (sc ^ (so & 7)) * 8;          // u16; + i*2048

    fl4 acc[8];
    #pragma unroll
    for (int ct = 0; ct < 8; ++ct) acc[ct] = (fl4){0.f, 0.f, 0.f, 0.f};
    fl4 accs = (fl4){0.f, 0.f, 0.f, 0.f};
    const bh8 ones = {(short)0x3F80, (short)0x3F80, (short)0x3F80, (short)0x3F80,
                      (short)0x3F80, (short)0x3F80, (short)0x3F80, (short)0x3F80};

    // read-side swizzled chunk (u16 offset): row o=ct*16+lr has o&7 == lr&7
    const int ch8 = ((w * 4 + g) ^ (lr & 7)) * 8;

    // prologue: window 0 — H into regs, adj/edst into regs, H -> LDS
    float4 hr[8];
    #pragma unroll
    for (int i = 0; i < 8; ++i)
        hr[i] = *(const float4*)(sgl + (long)i * 16 * NN);
    int4  ajA0 = *(const int4*)(ajb + mw);
    int4  ajA1 = *(const int4*)(ajb + mw + 4);
    float4 edA0 = *(const float4*)(edb + mw);
    float4 edA1 = *(const float4*)(edb + mw + 4);
    #pragma unroll
    for (int i = 0; i < 8; ++i)
        *(float4*)(Hs + sldst + i * 2048) = hr[i];

    #pragma unroll 1
    for (int win = 0; win < 16; ++win) {
        __syncthreads();   // Hs[win] visible to all waves

        // issue next window's loads early (latency hides under this window)
        int4 ajB0 = {0,0,0,0}, ajB1 = {0,0,0,0};
        float4 edB0 = {0,0,0,0}, edB1 = {0,0,0,0};
        if (win < 15) {
            const int mn = (win + 1) * 128;
            #pragma unroll
            for (int i = 0; i < 8; ++i)
                hr[i] = *(const float4*)(sgl + (long)i * 16 * NN + mn);
            ajB0 = *(const int4*)(ajb + mn + mw);
            ajB1 = *(const int4*)(ajb + mn + mw + 4);
            edB0 = *(const float4*)(edb + mn + mw);
            edB1 = *(const float4*)(edb + mn + mw + 4);
        }

        // A-fragment from regs: P = adj>0 ? exp(leaky(es+ed)-M) : 0 (bf16 rn)
        const float pe[8] = {edA0.x, edA0.y, edA0.z, edA0.w,
                             edA1.x, edA1.y, edA1.z, edA1.w};
        const int   aa[8] = {ajA0.x, ajA0.y, ajA0.z, ajA0.w,
                             ajA1.x, ajA1.y, ajA1.z, ajA1.w};
        bh8u pa;
        #pragma unroll
        for (int jj = 0; jj < 4; ++jj) {
            const int j0 = 2 * jj, j1 = j0 + 1;
            const float x0 = es + pe[j0];
            const float x1 = es + pe[j1];
            const float l0 = fmaxf(x0, 0.01f * x0);
            const float l1 = fmaxf(x1, 0.01f * x1);
            const float v0 = (aa[j0] > 0) ? __expf(l0 - M) : 0.f;
            const float v1 = (aa[j1] > 0) ? __expf(l1 - M) : 0.f;
            float2 cf; cf.x = v0; cf.y = v1;
            __hip_bfloat162 r2 = __float22bfloat162_rn(cf);
            pa.u[jj] = *reinterpret_cast<unsigned*>(&r2);
        }

        // B-frags from swizzled LDS + 9 MFMAs
        #pragma unroll
        for (int ct = 0; ct < 8; ++ct) {
            const bh8 bf = *(const bh8*)(Hs + (ct * 16 + lr) * 128 + ch8);
            acc[ct] = __builtin_amdgcn_mfma_f32_16x16x32_bf16(pa.v, bf, acc[ct], 0, 0, 0);
        }
        accs = __builtin_amdgcn_mfma_f32_16x16x32_bf16(pa.v, ones, accs, 0, 0, 0);

        __syncthreads();   // all waves done reading Hs[win]

        if (win < 15) {
            #pragma unroll
            for (int i = 0; i < 8; ++i)
                *(float4*)(Hs + sldst + i * 2048) = hr[i];
            ajA0 = ajB0; ajA1 = ajB1; edA0 = edB0; edA1 = edB1;
        }
    }

    // publish partials. C/D layout: col = ct*16+lr, row = g*4+reg  [m89/m91]
    if (lr == 0) {
        #pragma unroll
        for (int reg = 0; reg < 4; ++reg)
            psum_sh[w][g * 4 + reg] = accs[reg];
    }
    #pragma unroll
    for (int ct = 0; ct < 8; ++ct)
        #pragma unroll
        for (int reg = 0; reg < 4; ++reg)
            accbuf[w][g * 4 + reg][ct * 16 + lr] = acc[ct][reg];
    __syncthreads();

    // epilogue: sum the 4 m-split partials, scale, write (512 f4 / 256 thr)
    #pragma unroll
    for (int rep = 0; rep < 2; ++rep) {
        const int idx = t + 256 * rep;
        const int r = idx >> 5;
        const int c4 = (idx & 31) * 4;
        const float4 s0 = *(const float4*)&accbuf[0][r][c4];
        const float4 s1 = *(const float4*)&accbuf[1][r][c4];
        const float4 s2 = *(const float4*)&accbuf[2][r][c4];
        const float4 s3 = *(const float4*)&accbuf[3][r][c4];
        const float ps = psum_sh[0][r] + psum_sh[1][r] + psum_sh[2][r] + psum_sh[3][r];
        const float sc = mask[b * NN + n0 + r] / ps;
        float4 o;
        o.x = (s0.x + s1.x + s2.x + s3.x) * sc;
        o.y = (s0.y + s1.y + s2.y + s3.y) * sc;
        o.z = (s0.z + s1.z + s2.z + s3.z) * sc;
        o.w = (s0.w + s1.w + s2.w + s3.w) * sc;
        *(float4*)&out[((long)b * NN + n0 + r) * FF + c4] = o;
    }
}

// ---------------------------------------------------------------------------
extern "C" void kernel_launch(void* const* d_in, const int* in_sizes, int n_in,
                              void* d_out, int out_size, void* d_ws, size_t ws_size,
                              hipStream_t stream)
{
    const float* feat = (const float*)d_in[0];
    const int*   adj  = (const int*)d_in[1];
    const float* mask = (const float*)d_in[2];
    const float* W    = (const float*)d_in[3];
    const float* bias = (const float*)d_in[4];
    const float* a    = (const float*)d_in[5];
    float* out = (float*)d_out;

    // ws: htg bf16 [8][128][2048] (4MB) | esrc | edst (f32 64KB each)
    u16*   htg  = (u16*)d_ws;
    float* esrc = (float*)(htg + (size_t)BB * FF * NN);
    float* edst = esrc + BB * NN;

    k_h   <<<BB * NN / 8, 256, 0, stream>>>(feat, W, bias, a, htg, esrc, edst);
    k_attn<<<BB * (NN / 16), 256, 0, stream>>>(adj, mask, htg, esrc, edst, out);
}

// Round 13
// 163.568 us; speedup vs baseline: 1.0315x; 1.0315x over previous
//
#include <hip/hip_runtime.h>
#include <hip/hip_bf16.h>

#define BB 8
#define NN 2048
#define FF 128

typedef short bh8 __attribute__((ext_vector_type(8)));
typedef float fl4 __attribute__((ext_vector_type(4)));
typedef unsigned short u16;
typedef unsigned long long u64;
typedef union { bh8 v; unsigned u[4]; } bh8u;

__device__ __forceinline__ u16 f2bf(float x) {
    unsigned u = __float_as_uint(x);
    return (u16)((u + 0x7FFFu + ((u >> 16) & 1u)) >> 16);
}

// ---------------------------------------------------------------------------
// kernel 1: adjacency bit-pack via ballot (R6 version — best measured).
// ---------------------------------------------------------------------------
__global__ __launch_bounds__(256) void k_pack(
    const int* __restrict__ adj, u64* __restrict__ bm)
{
    const int t = threadIdx.x;
    const int w = t >> 6, lane = t & 63;
    const long row0 = (long)blockIdx.x * 8;
    #pragma unroll 8
    for (int i = 0; i < 64; ++i) {
        const int row = 2 * w + (i >> 5);
        const int chunk = i & 31;
        const int av = adj[(row0 + row) * NN + chunk * 64 + lane];
        const u64 m64 = __ballot(av > 0);
        if (lane == 0) bm[(row0 + row) * 32 + chunk] = m64;
    }
}

// ---------------------------------------------------------------------------
// kernel 2: h = feat @ W + b -> htg bf16 transposed [b][o][n]; side outputs
// esrc, edst, eed = exp(edst), eed2 = exp(0.01*edst).  (R8 version.)
// ---------------------------------------------------------------------------
__global__ __launch_bounds__(256) void k_h(
    const float* __restrict__ feat, const float* __restrict__ W,
    const float* __restrict__ bias, const float* __restrict__ a,
    u16* __restrict__ htg, float* __restrict__ esrc, float* __restrict__ edst,
    float* __restrict__ eed, float* __restrict__ eed2)
{
    __shared__ float fsh[8][FF];
    __shared__ float red[2][2][8];
    const int t = threadIdx.x;
    const long row0 = (long)blockIdx.x * 8;

    ((float4*)&fsh[0][0])[t] = ((const float4*)(feat + row0 * FF))[t];
    __syncthreads();

    const int o = t & 127;
    const int half = t >> 7;
    float acc[4] = {0.f, 0.f, 0.f, 0.f};
    #pragma unroll 4
    for (int k = 0; k < FF; ++k) {
        const float w = W[k * FF + o];
        #pragma unroll
        for (int r = 0; r < 4; ++r)
            acc[r] = fmaf(fsh[half * 4 + r][k], w, acc[r]);
    }
    const float bo = bias[o];
    const float as = a[o];
    const float ad = a[FF + o];
    float ps[4], pd[4];
    #pragma unroll
    for (int r = 0; r < 4; ++r) {
        acc[r] += bo;
        ps[r] = acc[r] * as;
        pd[r] = acc[r] * ad;
    }
    {
        const int bI = (int)(row0 >> 11);
        const int nloc = (int)(row0 & 2047) + half * 4;
        ushort4 hv;
        hv.x = f2bf(acc[0]); hv.y = f2bf(acc[1]);
        hv.z = f2bf(acc[2]); hv.w = f2bf(acc[3]);
        *(ushort4*)&htg[((long)bI * FF + o) * NN + nloc] = hv;
    }
    #pragma unroll
    for (int r = 0; r < 4; ++r) {
        #pragma unroll
        for (int off = 32; off > 0; off >>= 1) {
            ps[r] += __shfl_down(ps[r], off, 64);
            pd[r] += __shfl_down(pd[r], off, 64);
        }
    }
    const int wv = (t >> 6) & 1;
    if ((t & 63) == 0) {
        #pragma unroll
        for (int r = 0; r < 4; ++r) {
            red[half][wv][r]     = ps[r];
            red[half][wv][4 + r] = pd[r];
        }
    }
    __syncthreads();
    if (t < 16) {
        const int hh = t >> 3, idx = t & 7;
        const float v = red[hh][0][idx] + red[hh][1][idx];
        const long row = row0 + hh * 4 + (idx & 3);
        if (idx < 4) {
            esrc[row] = v;
        } else {
            edst[row] = v;
            eed[row]  = __expf(v);
            eed2[row] = __expf(0.01f * v);
        }
    }
}

// ---------------------------------------------------------------------------
// kernel 3: ZERO-sync attn. Wave = 16 rows x 32 cols x all m. Grid 1024,
// launch_bounds(256,4) -> 4 blocks/CU = 16 waves/CU, ~90 VGPR, no LDS, no
// barriers, no cross-wave traffic. Per 32-m chunk: tiny named reg-struct
// (bm u32 + 4 table float4 + 2 B-frags), prefetched 1 chunk ahead.
// P = bit ? max(A*E, Bv*F) : 0 (exp-table identity, R8/R9-validated);
// psum per-wave via ones-MFMA (R10-validated).
// ---------------------------------------------------------------------------
struct CR {
    unsigned bw;
    float4 E0, E1, F0, F1;
    bh8 bf0, bf1;
};

__device__ __forceinline__ void loadCR(CR& r, int c, const unsigned* bmrow32,
    const float* Ee, const float* Ff, const u16* hrow0, const u16* hrow1, int goff)
{
    const int m = c * 32 + goff;
    r.bw = bmrow32[c];
    r.E0 = *(const float4*)(Ee + m);
    r.E1 = *(const float4*)(Ee + m + 4);
    r.F0 = *(const float4*)(Ff + m);
    r.F1 = *(const float4*)(Ff + m + 4);
    r.bf0 = *(const bh8*)(hrow0 + m);
    r.bf1 = *(const bh8*)(hrow1 + m);
}

__device__ __forceinline__ void computeCR(const CR& r, int g, float A, float Bv,
    fl4& a0, fl4& a1, fl4& as, bh8 ones)
{
    const unsigned by = (r.bw >> (8 * g)) & 0xFFu;
    const float pe[8] = {r.E0.x, r.E0.y, r.E0.z, r.E0.w,
                         r.E1.x, r.E1.y, r.E1.z, r.E1.w};
    const float pf[8] = {r.F0.x, r.F0.y, r.F0.z, r.F0.w,
                         r.F1.x, r.F1.y, r.F1.z, r.F1.w};
    bh8u pa;
    #pragma unroll
    for (int jj = 0; jj < 4; ++jj) {
        const int j0 = 2 * jj, j1 = j0 + 1;
        const float v0 = ((by >> j0) & 1u) ? fmaxf(A * pe[j0], Bv * pf[j0]) : 0.f;
        const float v1 = ((by >> j1) & 1u) ? fmaxf(A * pe[j1], Bv * pf[j1]) : 0.f;
        float2 cf; cf.x = v0; cf.y = v1;
        __hip_bfloat162 r2 = __float22bfloat162_rn(cf);
        pa.u[jj] = *reinterpret_cast<unsigned*>(&r2);
    }
    a0 = __builtin_amdgcn_mfma_f32_16x16x32_bf16(pa.v, r.bf0, a0, 0, 0, 0);
    a1 = __builtin_amdgcn_mfma_f32_16x16x32_bf16(pa.v, r.bf1, a1, 0, 0, 0);
    as = __builtin_amdgcn_mfma_f32_16x16x32_bf16(pa.v, ones, as, 0, 0, 0);
}

__global__ __launch_bounds__(256, 4) void k_attn(
    const u64* __restrict__ bm, const float* __restrict__ mask,
    const u16* __restrict__ htg, const float* __restrict__ esrc,
    const float* __restrict__ edst, const float* __restrict__ eed,
    const float* __restrict__ eed2, float* __restrict__ out)
{
    const int t = threadIdx.x;
    const int b = blockIdx.x & 7;               // batch -> XCD affinity
    const int n0 = (blockIdx.x >> 3) * 16;      // 128 row-tiles per batch
    const int ch = t >> 6;                      // wave's 32-col slice
    const int lane = t & 63;
    const int lr = lane & 15, g = lane >> 4;

    // per-wave gmax over edst[b][:] (8 KB, L1/L2-hot)
    float gmx = -3.4e38f;
    {
        const float4* edp4 = (const float4*)(edst + b * NN);
        #pragma unroll
        for (int i = 0; i < 8; ++i) {
            const float4 v = edp4[lane + 64 * i];
            gmx = fmaxf(gmx, fmaxf(fmaxf(v.x, v.y), fmaxf(v.z, v.w)));
        }
        #pragma unroll
        for (int off = 32; off > 0; off >>= 1)
            gmx = fmaxf(gmx, __shfl_xor(gmx, off, 64));
    }

    const float es = esrc[b * NN + n0 + lr];     // this lane's P-row constant
    const float mt0 = es + gmx;
    const float M = fmaxf(mt0, 0.01f * mt0);     // leaky(es+gmax) >= rowmax
    const float A  = __expf(es - M);
    const float Bv = __expf(0.01f * es - M);

    const float* Ee = eed  + b * NN;
    const float* Ff = eed2 + b * NN;
    const u16* hB = htg + (long)b * FF * NN;
    const u16* hrow0 = hB + (long)(ch * 32 + lr) * NN;        // ct=0 row
    const u16* hrow1 = hB + (long)(ch * 32 + 16 + lr) * NN;   // ct=1 row
    const unsigned* bmrow32 = (const unsigned*)(bm + ((long)b * NN + n0 + lr) * 32);
    const int goff = g * 8;

    fl4 a0 = (fl4){0.f, 0.f, 0.f, 0.f};
    fl4 a1 = (fl4){0.f, 0.f, 0.f, 0.f};
    fl4 as = (fl4){0.f, 0.f, 0.f, 0.f};
    const bh8 ones = {(short)0x3F80, (short)0x3F80, (short)0x3F80, (short)0x3F80,
                      (short)0x3F80, (short)0x3F80, (short)0x3F80, (short)0x3F80};

    CR ra, rb;
    loadCR(ra, 0, bmrow32, Ee, Ff, hrow0, hrow1, goff);

    #pragma unroll 1
    for (int c = 0; c < 64; c += 2) {
        loadCR(rb, c + 1, bmrow32, Ee, Ff, hrow0, hrow1, goff);
        computeCR(ra, g, A, Bv, a0, a1, as, ones);
        loadCR(ra, (c + 2) & 63, bmrow32, Ee, Ff, hrow0, hrow1, goff);
        computeCR(rb, g, A, Bv, a0, a1, as, ones);
    }

    // epilogue: fully lane-local. C/D layout: col = ct*16 + lr,
    // row = g*4 + reg [m89/m91]; accs[reg] = rowsum(P row g*4+reg) same lane.
    const long obase = ((long)b * NN + n0) * FF + ch * 32;
    #pragma unroll
    for (int reg = 0; reg < 4; ++reg) {
        const int row = g * 4 + reg;
        const float sc = mask[b * NN + n0 + row] / as[reg];
        out[obase + (long)row * FF + lr]      = a0[reg] * sc;
        out[obase + (long)row * FF + 16 + lr] = a1[reg] * sc;
    }
}

// ---------------------------------------------------------------------------
extern "C" void kernel_launch(void* const* d_in, const int* in_sizes, int n_in,
                              void* d_out, int out_size, void* d_ws, size_t ws_size,
                              hipStream_t stream)
{
    const float* feat = (const float*)d_in[0];
    const int*   adj  = (const int*)d_in[1];
    const float* mask = (const float*)d_in[2];
    const float* W    = (const float*)d_in[3];
    const float* bias = (const float*)d_in[4];
    const float* a    = (const float*)d_in[5];
    float* out = (float*)d_out;

    // ws: htg bf16 [8][128][2048] | esrc | edst | eed | eed2 (f32 64KB each) | bm 4MB
    u16*   htg  = (u16*)d_ws;
    float* esrc = (float*)(htg + (size_t)BB * FF * NN);
    float* edst = esrc + BB * NN;
    float* eed  = edst + BB * NN;
    float* eed2 = eed + BB * NN;
    u64*   bmp  = (u64*)(eed2 + BB * NN);

    k_pack<<<BB * NN / 8, 256, 0, stream>>>(adj, bmp);
    k_h   <<<BB * NN / 8, 256, 0, stream>>>(feat, W, bias, a, htg, esrc, edst, eed, eed2);
    k_attn<<<BB * (NN / 16), 256, 0, stream>>>(bmp, mask, htg, esrc, edst, eed, eed2, out);
}

// Round 14
// 90.628 us; speedup vs baseline: 1.8616x; 1.8048x over previous
//
#include <hip/hip_runtime.h>
#include <hip/hip_bf16.h>

#define BB 8
#define NN 2048
#define FF 128

typedef short bh8 __attribute__((ext_vector_type(8)));
typedef float fl4 __attribute__((ext_vector_type(4)));
typedef unsigned short u16;
typedef unsigned long long u64;
typedef union { bh8 v; unsigned u[4]; } bh8u;

__device__ __forceinline__ u16 f2bf(float x) {
    unsigned u = __float_as_uint(x);
    return (u16)((u + 0x7FFFu + ((u >> 16) & 1u)) >> 16);
}

// 16-byte load the compiler cannot sink or elide.
#define GL16(dst, p) \
    asm volatile("global_load_dwordx4 %0, %1, off" : "=v"(dst) : "v"(p) : "memory")

// ---------------------------------------------------------------------------
// kernel 1: adjacency bit-pack via ballot (R6 version — best measured).
// ---------------------------------------------------------------------------
__global__ __launch_bounds__(256) void k_pack(
    const int* __restrict__ adj, u64* __restrict__ bm)
{
    const int t = threadIdx.x;
    const int w = t >> 6, lane = t & 63;
    const long row0 = (long)blockIdx.x * 8;
    #pragma unroll 8
    for (int i = 0; i < 64; ++i) {
        const int row = 2 * w + (i >> 5);
        const int chunk = i & 31;
        const int av = adj[(row0 + row) * NN + chunk * 64 + lane];
        const u64 m64 = __ballot(av > 0);
        if (lane == 0) bm[(row0 + row) * 32 + chunk] = m64;
    }
}

// ---------------------------------------------------------------------------
// kernel 2: h = feat @ W + b -> htg bf16 transposed [b][o][n]; esrc, edst.
// (R6 version — best measured.)
// ---------------------------------------------------------------------------
__global__ __launch_bounds__(256) void k_h(
    const float* __restrict__ feat, const float* __restrict__ W,
    const float* __restrict__ bias, const float* __restrict__ a,
    u16* __restrict__ htg, float* __restrict__ esrc, float* __restrict__ edst)
{
    __shared__ float fsh[8][FF];
    __shared__ float red[2][2][8];
    const int t = threadIdx.x;
    const long row0 = (long)blockIdx.x * 8;

    ((float4*)&fsh[0][0])[t] = ((const float4*)(feat + row0 * FF))[t];
    __syncthreads();

    const int o = t & 127;
    const int half = t >> 7;
    float acc[4] = {0.f, 0.f, 0.f, 0.f};
    #pragma unroll 4
    for (int k = 0; k < FF; ++k) {
        const float w = W[k * FF + o];
        #pragma unroll
        for (int r = 0; r < 4; ++r)
            acc[r] = fmaf(fsh[half * 4 + r][k], w, acc[r]);
    }
    const float bo = bias[o];
    const float as = a[o];
    const float ad = a[FF + o];
    float ps[4], pd[4];
    #pragma unroll
    for (int r = 0; r < 4; ++r) {
        acc[r] += bo;
        ps[r] = acc[r] * as;
        pd[r] = acc[r] * ad;
    }
    {
        const int bI = (int)(row0 >> 11);
        const int nloc = (int)(row0 & 2047) + half * 4;
        ushort4 hv;
        hv.x = f2bf(acc[0]); hv.y = f2bf(acc[1]);
        hv.z = f2bf(acc[2]); hv.w = f2bf(acc[3]);
        *(ushort4*)&htg[((long)bI * FF + o) * NN + nloc] = hv;
    }
    #pragma unroll
    for (int r = 0; r < 4; ++r) {
        #pragma unroll
        for (int off = 32; off > 0; off >>= 1) {
            ps[r] += __shfl_down(ps[r], off, 64);
            pd[r] += __shfl_down(pd[r], off, 64);
        }
    }
    const int wv = (t >> 6) & 1;
    if ((t & 63) == 0) {
        #pragma unroll
        for (int r = 0; r < 4; ++r) {
            red[half][wv][r]     = ps[r];
            red[half][wv][4 + r] = pd[r];
        }
    }
    __syncthreads();
    if (t < 16) {
        const int hh = t >> 3, idx = t & 7;
        const float v = red[hh][0][idx] + red[hh][1][idx];
        const long row = row0 + hh * 4 + (idx & 3);
        if (idx < 4) esrc[row] = v;
        else         edst[row] = v;
    }
}

// ---------------------------------------------------------------------------
// kernel 3: R6 structure (RB=32, 4 waves m-split, 8 ct) + ASM-FORCED depth-1
// load pipeline: per step, next step's 10-load batch (8 B-frags + 2 edst f4)
// issued via volatile asm; counted s_waitcnt vmcnt(10/12) + sched_barrier(0);
// then A-build + 18 MFMAs on the completed batch. Parity-named double
// buffers (compile-time selects). Dummy wrap loads keep counts uniform;
// vmcnt(0) drain after the loop. psum via ones-MFMA.
// ---------------------------------------------------------------------------
__global__ __launch_bounds__(256, 2) void k_attn(
    const u64* __restrict__ bm, const float* __restrict__ mask,
    const u16* __restrict__ htg, const float* __restrict__ esrc,
    const float* __restrict__ edst, float* __restrict__ out)
{
    __shared__ float accbuf[4][32][FF + 4];   // 67.6 KB
    __shared__ float psum_sh[4][32];

    const int t = threadIdx.x;
    const int b = blockIdx.x & 7;               // batch -> XCD affinity
    const int n0 = (blockIdx.x >> 3) * 32;      // 64 row-tiles per batch
    const int w = t >> 6, lane = t & 63;
    const int lr = lane & 15, g = lane >> 4;

    // per-wave gmax over edst[b][:] (8 KB, cache-hot)
    float gmx = -3.4e38f;
    {
        const float4* edp4 = (const float4*)(edst + b * NN);
        #pragma unroll
        for (int i = 0; i < 8; ++i) {
            const float4 v = edp4[lane + 64 * i];
            gmx = fmaxf(gmx, fmaxf(fmaxf(v.x, v.y), fmaxf(v.z, v.w)));
        }
        #pragma unroll
        for (int off = 32; off > 0; off >>= 1)
            gmx = fmaxf(gmx, __shfl_xor(gmx, off, 64));
    }

    const float es0 = esrc[b * NN + n0 + lr];
    const float es1 = esrc[b * NN + n0 + 16 + lr];
    const float m0t = es0 + gmx; const float M0 = fmaxf(m0t, 0.01f * m0t);
    const float m1t = es1 + gmx; const float M1 = fmaxf(m1t, 0.01f * m1t);

    const u16*   hB  = htg + (long)b * FF * NN;
    const float* edb = edst + b * NN;
    const uint4* bmq0 = (const uint4*)(bm + ((long)b * NN + n0 + lr) * 32);
    const uint4* bmq1 = (const uint4*)(bm + ((long)b * NN + n0 + 16 + lr) * 32);

    const u16* hrow[8];
    #pragma unroll
    for (int ct = 0; ct < 8; ++ct) hrow[ct] = hB + (long)(ct * 16 + lr) * NN;

    fl4 acc0[8], acc1[8];
    #pragma unroll
    for (int ct = 0; ct < 8; ++ct) {
        acc0[ct] = (fl4){0.f, 0.f, 0.f, 0.f};
        acc1[ct] = (fl4){0.f, 0.f, 0.f, 0.f};
    }
    fl4 accs0 = (fl4){0.f, 0.f, 0.f, 0.f};
    fl4 accs1 = (fl4){0.f, 0.f, 0.f, 0.f};
    const bh8 ones = {(short)0x3F80, (short)0x3F80, (short)0x3F80, (short)0x3F80,
                      (short)0x3F80, (short)0x3F80, (short)0x3F80, (short)0x3F80};

    bh8    bufA[8], bufB[8];
    float4 edA0, edA1, edB0, edB1;
    uint4  bqA0, bqA1, bqB0, bqB1;

    const int wbase = w * 128 + g * 8;           // wave/lane m-offset, step 0

    // clean vmem slate: all compiler-emitted loads drained; bookkeeping = 0
    asm volatile("s_waitcnt vmcnt(0)" ::: "memory");

    // prologue: bq(it=0) + batch(step 0)
    GL16(bqA0, bmq0 + w);
    GL16(bqA1, bmq1 + w);
    #pragma unroll
    for (int ct = 0; ct < 8; ++ct) GL16(bufA[ct], hrow[ct] + wbase);
    GL16(edA0, edb + wbase);
    GL16(edA1, edb + wbase + 4);

    #pragma unroll 1
    for (int hf = 0; hf < 2; ++hf) {
        #pragma unroll
        for (int sh = 0; sh < 8; ++sh) {
            const int kc  = sh & 3;
            const int itn = (hf * 2 + ((sh + 1) >> 2)) & 3;  // next-step it (wrapped)
            const int kcn = (sh + 1) & 3;

            // 1) bitmask prefetch for it+1 at kc==2 (dummy wrap at the end)
            if (kc == 2) {
                const int itb = (hf * 2 + (sh >> 2) + 1) & 3;
                if ((((sh >> 2) + 1) & 1) != 0) {
                    GL16(bqB0, bmq0 + w + 4 * itb);
                    GL16(bqB1, bmq1 + w + 4 * itb);
                } else {
                    GL16(bqA0, bmq0 + w + 4 * itb);
                    GL16(bqA1, bmq1 + w + 4 * itb);
                }
            }

            // 2) issue batch(s+1): 8 B-frags + 2 edst float4
            {
                const int offn = itn * 512 + kcn * 32 + wbase;
                if (((sh + 1) & 1) != 0) {
                    #pragma unroll
                    for (int ct = 0; ct < 8; ++ct) GL16(bufB[ct], hrow[ct] + offn);
                    GL16(edB0, edb + offn);
                    GL16(edB1, edb + offn + 4);
                } else {
                    #pragma unroll
                    for (int ct = 0; ct < 8; ++ct) GL16(bufA[ct], hrow[ct] + offn);
                    GL16(edA0, edb + offn);
                    GL16(edA1, edb + offn + 4);
                }
            }

            // 3) wait: batch(s) complete, batch(s+1) [+bq] stays in flight
            if (kc == 2) asm volatile("s_waitcnt vmcnt(12)" ::: "memory");
            else         asm volatile("s_waitcnt vmcnt(10)" ::: "memory");
            __builtin_amdgcn_sched_barrier(0);

            // 4) A-build (this step's parity buffers; compile-time selects)
            const float4 e0 = ((sh & 1) != 0) ? edB0 : edA0;
            const float4 e1 = ((sh & 1) != 0) ? edB1 : edA1;
            const uint4  q0v = (((sh >> 2) & 1) != 0) ? bqB0 : bqA0;
            const uint4  q1v = (((sh >> 2) & 1) != 0) ? bqB1 : bqA1;
            const unsigned q0 = (kc == 0) ? q0v.x : (kc == 1) ? q0v.y
                              : (kc == 2) ? q0v.z : q0v.w;
            const unsigned q1 = (kc == 0) ? q1v.x : (kc == 1) ? q1v.y
                              : (kc == 2) ? q1v.z : q1v.w;
            const unsigned by0 = (q0 >> (8 * g)) & 0xFFu;
            const unsigned by1 = (q1 >> (8 * g)) & 0xFFu;
            const float pe[8] = {e0.x, e0.y, e0.z, e0.w, e1.x, e1.y, e1.z, e1.w};
            bh8u pa, pb;
            #pragma unroll
            for (int jj = 0; jj < 4; ++jj) {
                const int j0 = 2 * jj, j1 = j0 + 1;
                const float x00 = es0 + pe[j0], x01 = es0 + pe[j1];
                const float x10 = es1 + pe[j0], x11 = es1 + pe[j1];
                const float l00 = fmaxf(x00, 0.01f * x00);
                const float l01 = fmaxf(x01, 0.01f * x01);
                const float l10 = fmaxf(x10, 0.01f * x10);
                const float l11 = fmaxf(x11, 0.01f * x11);
                const float v00 = ((by0 >> j0) & 1u) ? __expf(l00 - M0) : 0.f;
                const float v01 = ((by0 >> j1) & 1u) ? __expf(l01 - M0) : 0.f;
                const float v10 = ((by1 >> j0) & 1u) ? __expf(l10 - M1) : 0.f;
                const float v11 = ((by1 >> j1) & 1u) ? __expf(l11 - M1) : 0.f;
                float2 c0f; c0f.x = v00; c0f.y = v01;
                float2 c1f; c1f.x = v10; c1f.y = v11;
                __hip_bfloat162 r0 = __float22bfloat162_rn(c0f);
                __hip_bfloat162 r1 = __float22bfloat162_rn(c1f);
                pa.u[jj] = *reinterpret_cast<unsigned*>(&r0);
                pb.u[jj] = *reinterpret_cast<unsigned*>(&r1);
            }

            // 5) 16 output MFMAs + 2 ones-MFMAs on this step's buffer
            #pragma unroll
            for (int ct = 0; ct < 8; ++ct) {
                const bh8 bf = ((sh & 1) != 0) ? bufB[ct] : bufA[ct];
                acc0[ct] = __builtin_amdgcn_mfma_f32_16x16x32_bf16(pa.v, bf, acc0[ct], 0, 0, 0);
                acc1[ct] = __builtin_amdgcn_mfma_f32_16x16x32_bf16(pb.v, bf, acc1[ct], 0, 0, 0);
            }
            accs0 = __builtin_amdgcn_mfma_f32_16x16x32_bf16(pa.v, ones, accs0, 0, 0, 0);
            accs1 = __builtin_amdgcn_mfma_f32_16x16x32_bf16(pb.v, ones, accs1, 0, 0, 0);
        }
    }

    // drain dummy wrap loads before their dest regs can be reused
    asm volatile("s_waitcnt vmcnt(0)" ::: "memory");
    __builtin_amdgcn_sched_barrier(0);

    // publish partials. C/D layout: col = ct*16+lr, row = g*4+reg  [m89/m91]
    if (lr == 0) {
        #pragma unroll
        for (int reg = 0; reg < 4; ++reg) {
            psum_sh[w][g * 4 + reg]      = accs0[reg];
            psum_sh[w][16 + g * 4 + reg] = accs1[reg];
        }
    }
    #pragma unroll
    for (int ct = 0; ct < 8; ++ct)
        #pragma unroll
        for (int reg = 0; reg < 4; ++reg) {
            accbuf[w][g * 4 + reg][ct * 16 + lr]      = acc0[ct][reg];
            accbuf[w][16 + g * 4 + reg][ct * 16 + lr] = acc1[ct][reg];
        }
    __syncthreads();

    // epilogue: sum 4 wave-partials, scale, write. 1024 float4 / 256 threads.
    #pragma unroll
    for (int rep = 0; rep < 4; ++rep) {
        const int idx = t + 256 * rep;
        const int r = idx >> 5;
        const int c4 = (idx & 31) * 4;
        const float4 s0 = *(const float4*)&accbuf[0][r][c4];
        const float4 s1 = *(const float4*)&accbuf[1][r][c4];
        const float4 s2 = *(const float4*)&accbuf[2][r][c4];
        const float4 s3 = *(const float4*)&accbuf[3][r][c4];
        const float ps = psum_sh[0][r] + psum_sh[1][r] + psum_sh[2][r] + psum_sh[3][r];
        const float sc = mask[b * NN + n0 + r] / ps;
        float4 o;
        o.x = (s0.x + s1.x + s2.x + s3.x) * sc;
        o.y = (s0.y + s1.y + s2.y + s3.y) * sc;
        o.z = (s0.z + s1.z + s2.z + s3.z) * sc;
        o.w = (s0.w + s1.w + s2.w + s3.w) * sc;
        *(float4*)&out[((long)b * NN + n0 + r) * FF + c4] = o;
    }
}

// ---------------------------------------------------------------------------
extern "C" void kernel_launch(void* const* d_in, const int* in_sizes, int n_in,
                              void* d_out, int out_size, void* d_ws, size_t ws_size,
                              hipStream_t stream)
{
    const float* feat = (const float*)d_in[0];
    const int*   adj  = (const int*)d_in[1];
    const float* mask = (const float*)d_in[2];
    const float* W    = (const float*)d_in[3];
    const float* bias = (const float*)d_in[4];
    const float* a    = (const float*)d_in[5];
    float* out = (float*)d_out;

    // ws: htg bf16 [8][128][2048] (4MB) | esrc | edst (f32 64KB each) | bm 4MB
    u16*   htg  = (u16*)d_ws;
    float* esrc = (float*)(htg + (size_t)BB * FF * NN);
    float* edst = esrc + BB * NN;
    u64*   bmp  = (u64*)(edst + BB * NN);

    k_pack<<<BB * NN / 8, 256, 0, stream>>>(adj, bmp);
    k_h   <<<BB * NN / 8, 256, 0, stream>>>(feat, W, bias, a, htg, esrc, edst);
    k_attn<<<BB * (NN / 32), 256, 0, stream>>>(bmp, mask, htg, esrc, edst, out);
}